// Round 4
// baseline (155.888 us; speedup 1.0000x reference)
//
#include <hip/hip_runtime.h>
#include <math.h>

#define H 512
#define W 512
#define IMG (H*W)
#define NIMG 32           // 16 images from y_hat + 16 from y

typedef unsigned long long u64;

__device__ __forceinline__ int reflect_idx(int i, int n) {
    // jnp.pad mode="reflect": -1 -> 1, -2 -> 2, n -> n-2, n+1 -> n-3
    if (i < 0) i = -i;
    if (i >= n) i = 2 * n - 2 - i;
    return i;
}

// Composed 7-tap kernels: blur(g, 5-tap) composed with sobel [1,2,1]/[-1,0,1].
// Symmetric  (g * [1,2,1]):  [S0,S1,S2,S3,S2,S1,S0]
// Antisym    (g * [-1,0,1]): [-A1,-A2,-A3,0,A3,A2,A1]
#define S0 0.05448868454964294f
#define S1 0.35317871110251920f
#define S2 0.94551131545035710f
#define S3 1.29364257779496160f
#define A1 0.05448868454964294f
#define A2 0.24420134200323332f
#define A3 0.34813126234460456f

// ---------------------------------------------------------------------------
// Kernel 1: gray -> (separable 7x7) gx,gy -> mag+dir -> NMS -> thresholds ->
// strong/weak bitplanes. Tile 64x32, block (64,8), 4 rows/thread.
// LDS: sg[42][76] (gray, halo 4/5), hxy[42][68] float2 (h-pass out),
//      sm[36][68] + sbin[36][68] alias sg (gray dead after h-pass).
// ---------------------------------------------------------------------------
#define TY 32

__global__ __launch_bounds__(512) void k_edges(const float* __restrict__ yhat,
                                               const float* __restrict__ yy,
                                               u64* __restrict__ strongP,
                                               u64* __restrict__ weakP) {
    __shared__ __align__(16) char lds[12768 + 22848];
    float (*sg)[76] = (float (*)[76])lds;                         // 42 x 76 f32
    float (*hxy)[68][2] = (float (*)[68][2])(lds + 12768);        // 42 x 68 f32x2
    float (*sm)[68] = (float (*)[68])lds;                         // 36 x 68 f32 (alias)
    unsigned char (*sbin)[68] = (unsigned char (*)[68])(lds + 9792); // 36 x 68 u8

    const int n = blockIdx.z;
    const float* src = (n < 16) ? (yhat + (size_t)n * 3 * IMG)
                                : (yy + (size_t)(n - 16) * 3 * IMG);
    const int x0 = blockIdx.x * 64;
    const int y0 = blockIdx.y * TY;
    const int tx = threadIdx.x, ty = threadIdx.y;
    const int tid = ty * 64 + tx;

    // ---- stage gray: rows y0-4 .. y0+37 (42), cols x0-4 .. x0+67 (72) ----
    const int ixA = reflect_idx(x0 - 4 + tx, W);
    const int ixB = reflect_idx(x0 + 60 + tx, W);   // only tx<8 used
#pragma unroll
    for (int k = 0; k < 6; k++) {
        int sy = ty + 8 * k;
        if (sy < 42) {
            int iy = reflect_idx(y0 - 4 + sy, H);
            const float* row = src + iy * W;
            float r = row[ixA], g = row[IMG + ixA], b = row[2 * IMG + ixA];
            sg[sy][tx] = 0.299f * r + 0.587f * g + 0.114f * b;
            if (tx < 8) {
                float r2 = row[ixB], g2 = row[IMG + ixB], b2 = row[2 * IMG + ixB];
                sg[sy][64 + tx] = 0.299f * r2 + 0.587f * g2 + 0.114f * b2;
            }
        }
    }
    __syncthreads();

    // ---- h-pass: 42 rows x 68 cols (66 used), 4 outputs/task, 714 tasks ----
    // h col sx <-> image col x0-1+sx; needs gray idx sx..sx+6
    for (int t = tid; t < 714; t += 512) {
        int sy = t / 17, g = t % 17;
        const float4* p = (const float4*)&sg[sy][0];
        float4 q0 = p[g], q1 = p[g + 1], q2 = p[g + 2];
        float w[12] = {q0.x, q0.y, q0.z, q0.w, q1.x, q1.y, q1.z, q1.w,
                       q2.x, q2.y, q2.z, q2.w};
#pragma unroll
        for (int j = 0; j < 4; j++) {
            float hx = A3 * (w[j + 4] - w[j + 2]) + A2 * (w[j + 5] - w[j + 1])
                     + A1 * (w[j + 6] - w[j + 0]);
            float hy = S3 * w[j + 3] + S2 * (w[j + 4] + w[j + 2])
                     + S1 * (w[j + 5] + w[j + 1]) + S0 * (w[j + 6] + w[j + 0]);
            *(float2*)&hxy[sy][4 * g + j][0] = make_float2(hx, hy);
        }
    }
    __syncthreads();

    // ---- v-pass: mag rows 0..35 (image y0-1+my), cols 0..65 (image x0-1+c),
    //      4 row-outputs/task, 9 groups x 66 cols = 594 tasks ----
    for (int t = tid; t < 594; t += 512) {
        int rg = t / 66, c = t % 66;
        float hx[10], hy[10];
#pragma unroll
        for (int i = 0; i < 10; i++) {
            float2 v = *(const float2*)&hxy[4 * rg + i][c][0];
            hx[i] = v.x; hy[i] = v.y;
        }
        int imgcol = x0 - 1 + c;
        bool colok = (unsigned)imgcol < (unsigned)W;
#pragma unroll
        for (int j = 0; j < 4; j++) {
            int my = 4 * rg + j;
            float gx = S3 * hx[j + 3] + S2 * (hx[j + 4] + hx[j + 2])
                     + S1 * (hx[j + 5] + hx[j + 1]) + S0 * (hx[j + 6] + hx[j + 0]);
            float gy = A3 * (hy[j + 4] - hy[j + 2]) + A2 * (hy[j + 5] - hy[j + 1])
                     + A1 * (hy[j + 6] - hy[j + 0]);
            int imgrow = y0 - 1 + my;
            bool ok = colok && ((unsigned)imgrow < (unsigned)H);
            float m = ok ? sqrtf(gx * gx + gy * gy + 1e-12f) : 0.f;
            sm[my][c] = m;
            // direction -> neighbor offset d in elements of sm (stride 68)
            float ax = fabsf(gx), ay = fabsf(gy);
            int d;
            if (ay <= 0.4142135623730951f * ax) d = 1;          // 0 deg
            else if (ay >= 2.414213562373095f * ax) d = 68;     // 90 deg
            else d = ((gx > 0.f) == (gy > 0.f)) ? 69 : 67;      // 45 / 135
            sbin[my][c] = (unsigned char)d;
        }
    }
    __syncthreads();

    // ---- NMS + double threshold + ballot ----
#pragma unroll
    for (int k = 0; k < 4; k++) {
        int ry = ty + 8 * k;   // 0..31
        const float* cp = &sm[ry + 1][tx + 1];
        float mag = cp[0];
        int d = sbin[ry + 1][tx + 1];
        float n1 = cp[d];
        float n2 = cp[-d];
        float nms = (mag >= n1 && mag >= n2) ? mag : 0.f;
        u64 strong = __ballot(nms >= 0.2f);
        u64 weak = __ballot(nms >= 0.1f);
        if (tx == 0) {
            size_t off = ((size_t)n * H + (y0 + ry)) * 8 + blockIdx.x;
            strongP[off] = strong;
            weakP[off] = weak;
        }
    }
}

// ---------------------------------------------------------------------------
// Kernel 2: bit-parallel hysteresis (10 iters, exact via light cone) + diff
// count. One wave per 32x32 tile per image-pair; lane l holds row ty0-10+l
// (52 active lanes) as a 64-bit window covering x0-10 .. x0+53.
// Per-block partial sums (NO global atomics).
// ---------------------------------------------------------------------------
__device__ __forceinline__ u64 ldw(const u64* p, int img, int y, int w, bool ok) {
    return (ok && w >= 0 && w < 8) ? p[((size_t)img * H + y) * 8 + w] : 0ULL;
}

__global__ __launch_bounds__(256) void k_hyst(const u64* __restrict__ strongP,
                                              const u64* __restrict__ weakP,
                                              unsigned int* __restrict__ partials) {
    __shared__ unsigned int part[4];
    const int wy = threadIdx.x >> 6;
    const int wave = blockIdx.x * 4 + wy;
    const int lane = threadIdx.x & 63;
    const int tile = wave & 255;
    const int pair = wave >> 8;          // 0..15
    const int tx0 = (tile & 15) * 32;
    const int ty0 = (tile >> 4) * 32;

    const int y = ty0 - 10 + lane;
    const bool rowok = (lane < 52) && (y >= 0) && (y < H);
    const int s = tx0 - 10;
    const int w0i = s >> 6;              // arithmetic shift: -10>>6 = -1
    const int r = s & 63;                // in {22,54}, never 0

    const int imgA = pair, imgB = pair + 16;
    u64 sA, wA, sB, wB;
    {
        u64 lo, hi;
        lo = ldw(strongP, imgA, y, w0i, rowok); hi = ldw(strongP, imgA, y, w0i + 1, rowok);
        sA = (lo >> r) | (hi << (64 - r));
        lo = ldw(weakP, imgA, y, w0i, rowok);   hi = ldw(weakP, imgA, y, w0i + 1, rowok);
        wA = (lo >> r) | (hi << (64 - r));
        lo = ldw(strongP, imgB, y, w0i, rowok); hi = ldw(strongP, imgB, y, w0i + 1, rowok);
        sB = (lo >> r) | (hi << (64 - r));
        lo = ldw(weakP, imgB, y, w0i, rowok);   hi = ldw(weakP, imgB, y, w0i + 1, rowok);
        wB = (lo >> r) | (hi << (64 - r));
    }

#pragma unroll
    for (int it = 0; it < 10; it++) {
        u64 up = __shfl_up(sA, 1), dn = __shfl_down(sA, 1);
        u64 t = up | sA | dn;
        sA |= (t | (t << 1) | (t >> 1)) & wA;
        up = __shfl_up(sB, 1); dn = __shfl_down(sB, 1);
        t = up | sB | dn;
        sB |= (t | (t << 1) | (t >> 1)) & wB;
    }

    // central 32x32: lanes 10..41, bits 10..41
    unsigned int c = 0;
    if (lane >= 10 && lane < 42) {
        const u64 mask = ((1ULL << 42) - (1ULL << 10));
        c = (unsigned int)__popcll((sA ^ sB) & mask);
    }
#pragma unroll
    for (int off = 32; off > 0; off >>= 1) c += __shfl_down(c, off);
    if (lane == 0) part[wy] = c;
    __syncthreads();
    if (threadIdx.x == 0)
        partials[blockIdx.x] = part[0] + part[1] + part[2] + part[3];
}

// ---------------------------------------------------------------------------
// Kernel 3: sum 1024 partials, scale, write scalar. One block.
// ---------------------------------------------------------------------------
__global__ __launch_bounds__(256) void k_final(const unsigned int* __restrict__ partials,
                                               float* __restrict__ out) {
    __shared__ unsigned int part[4];
    unsigned int c = 0;
    for (int i = threadIdx.x; i < 1024; i += 256) c += partials[i];
#pragma unroll
    for (int off = 32; off > 0; off >>= 1) c += __shfl_down(c, off);
    const int lane = threadIdx.x & 63;
    const int wy = threadIdx.x >> 6;
    if (lane == 0) part[wy] = c;
    __syncthreads();
    if (threadIdx.x == 0)
        out[0] = (float)(part[0] + part[1] + part[2] + part[3]) * (1.0f / 4194304.0f);
}

extern "C" void kernel_launch(void* const* d_in, const int* in_sizes, int n_in,
                              void* d_out, int out_size, void* d_ws, size_t ws_size,
                              hipStream_t stream) {
    const float* yhat = (const float*)d_in[0];
    const float* yy = (const float*)d_in[1];

    u64* strongP = (u64*)d_ws;                   // 32*512*8 u64 = 1 MB
    u64* weakP = strongP + (size_t)NIMG * H * 8; // 1 MB
    unsigned int* partials = (unsigned int*)(weakP + (size_t)NIMG * H * 8); // 4 KB

    dim3 eblk(64, 8);
    dim3 egrd(W / 64, H / TY, NIMG);
    k_edges<<<egrd, eblk, 0, stream>>>(yhat, yy, strongP, weakP);

    // 256 tiles x 16 pairs = 4096 waves, 4 waves/block
    k_hyst<<<1024, 256, 0, stream>>>(strongP, weakP, partials);
    k_final<<<1, 256, 0, stream>>>(partials, (float*)d_out);
}

// Round 5
// 142.794 us; speedup vs baseline: 1.0917x; 1.0917x over previous
//
#include <hip/hip_runtime.h>
#include <math.h>

#define H 512
#define W 512
#define IMG (H*W)
#define NIMG 32           // 16 images from y_hat + 16 from y

typedef unsigned long long u64;

__device__ __forceinline__ int reflect_idx(int i, int n) {
    // jnp.pad mode="reflect": -1 -> 1, -2 -> 2, n -> n-2, n+1 -> n-3
    if (i < 0) i = -i;
    if (i >= n) i = 2 * n - 2 - i;
    return i;
}

// Composed 7-tap kernels: blur(g, 5-tap) composed with sobel [1,2,1]/[-1,0,1].
// Symmetric  (g * [1,2,1]):  [S0,S1,S2,S3,S2,S1,S0]
// Antisym    (g * [-1,0,1]): [-A1,-A2,-A3,0,A3,A2,A1]
#define S0 0.05448868454964294f
#define S1 0.35317871110251920f
#define S2 0.94551131545035710f
#define S3 1.29364257779496160f
#define A1 0.05448868454964294f
#define A2 0.24420134200323332f
#define A3 0.34813126234460456f

// ---------------------------------------------------------------------------
// Kernel 1: gray -> (separable 7x7) gx,gy -> mag+dir -> NMS -> thresholds ->
// strong/weak bitplanes. Tile 64x32, block (64,8), 4 rows/thread.
// LDS: sg[42][80] (gray, cols = image x0-8..x0+67, 16B-aligned rows),
//      hxy[42][68] float2; sm[36][68] + sbin[36][68] alias sg.
// Bitplane layout: plane[img][word][row] (coalesced for k_hyst).
// ---------------------------------------------------------------------------
#define TY 32

__global__ __launch_bounds__(512) void k_edges(const float* __restrict__ yhat,
                                               const float* __restrict__ yy,
                                               u64* __restrict__ strongP,
                                               u64* __restrict__ weakP) {
    __shared__ __align__(16) char lds[13440 + 22848];
    float (*sg)[80] = (float (*)[80])lds;                         // 42 x 80 f32
    float (*hxy)[68][2] = (float (*)[68][2])(lds + 13440);        // 42 x 68 f32x2
    float (*sm)[68] = (float (*)[68])lds;                         // 36 x 68 f32 (alias)
    unsigned char (*sbin)[68] = (unsigned char (*)[68])(lds + 9792); // 36 x 68 u8

    const int n = blockIdx.z;
    const float* src = (n < 16) ? (yhat + (size_t)n * 3 * IMG)
                                : (yy + (size_t)(n - 16) * 3 * IMG);
    const int x0 = blockIdx.x * 64;
    const int y0 = blockIdx.y * TY;
    const int tx = threadIdx.x, ty = threadIdx.y;
    const int tid = ty * 64 + tx;

    // ---- stage gray: rows y0-4 .. y0+37 (42), cols x0-8 .. x0+67 (76) ----
    if (x0 >= 8 && x0 + 68 <= W) {
        // interior in x: vectorized float4 path (y-reflect is row-granular)
        for (int t = tid; t < 42 * 19; t += 512) {
            int sy = t / 19, f = t % 19;
            int iy = reflect_idx(y0 - 4 + sy, H);
            const float4* rp = (const float4*)(src + (size_t)iy * W + (x0 - 8));
            float4 r = rp[f];
            float4 g = rp[f + IMG / 4];
            float4 b = rp[f + 2 * (IMG / 4)];
            float4 gr;
            gr.x = 0.299f * r.x + 0.587f * g.x + 0.114f * b.x;
            gr.y = 0.299f * r.y + 0.587f * g.y + 0.114f * b.y;
            gr.z = 0.299f * r.z + 0.587f * g.z + 0.114f * b.z;
            gr.w = 0.299f * r.w + 0.587f * g.w + 0.114f * b.w;
            *(float4*)&sg[sy][4 * f] = gr;
        }
    } else {
        // x-border blocks: scalar reflect path
        for (int t = tid; t < 42 * 76; t += 512) {
            int sy = t / 76, c = t % 76;
            int iy = reflect_idx(y0 - 4 + sy, H);
            int ix = reflect_idx(x0 - 8 + c, W);
            const float* row = src + (size_t)iy * W;
            float r = row[ix], g = row[IMG + ix], b = row[2 * IMG + ix];
            sg[sy][c] = 0.299f * r + 0.587f * g + 0.114f * b;
        }
    }
    __syncthreads();

    // ---- h-pass: 42 rows x 17 groups of 4 cols; out col sx = image x0-1+sx,
    //      needs sg cols sx+7-3 .. sx+7+3 = 4g+4 .. 4g+13 (float4s g+1..g+3) ----
    for (int t = tid; t < 714; t += 512) {
        int sy = t / 17, g = t % 17;
        const float4* p = (const float4*)&sg[sy][0];
        float4 q0 = p[g + 1], q1 = p[g + 2], q2 = p[g + 3];
        float w[12] = {q0.x, q0.y, q0.z, q0.w, q1.x, q1.y, q1.z, q1.w,
                       q2.x, q2.y, q2.z, q2.w};
#pragma unroll
        for (int j = 0; j < 4; j++) {
            float hx = A3 * (w[j + 4] - w[j + 2]) + A2 * (w[j + 5] - w[j + 1])
                     + A1 * (w[j + 6] - w[j + 0]);
            float hy = S3 * w[j + 3] + S2 * (w[j + 4] + w[j + 2])
                     + S1 * (w[j + 5] + w[j + 1]) + S0 * (w[j + 6] + w[j + 0]);
            *(float2*)&hxy[sy][4 * g + j][0] = make_float2(hx, hy);
        }
    }
    __syncthreads();

    // ---- v-pass: mag rows 0..35 (image y0-1+my), cols 0..65 (image x0-1+c) ----
    for (int t = tid; t < 594; t += 512) {
        int rg = t / 66, c = t % 66;
        float hx[10], hy[10];
#pragma unroll
        for (int i = 0; i < 10; i++) {
            float2 v = *(const float2*)&hxy[4 * rg + i][c][0];
            hx[i] = v.x; hy[i] = v.y;
        }
        int imgcol = x0 - 1 + c;
        bool colok = (unsigned)imgcol < (unsigned)W;
#pragma unroll
        for (int j = 0; j < 4; j++) {
            int my = 4 * rg + j;
            float gx = S3 * hx[j + 3] + S2 * (hx[j + 4] + hx[j + 2])
                     + S1 * (hx[j + 5] + hx[j + 1]) + S0 * (hx[j + 6] + hx[j + 0]);
            float gy = A3 * (hy[j + 4] - hy[j + 2]) + A2 * (hy[j + 5] - hy[j + 1])
                     + A1 * (hy[j + 6] - hy[j + 0]);
            int imgrow = y0 - 1 + my;
            bool ok = colok && ((unsigned)imgrow < (unsigned)H);
            float m = ok ? sqrtf(gx * gx + gy * gy + 1e-12f) : 0.f;
            sm[my][c] = m;
            float ax = fabsf(gx), ay = fabsf(gy);
            int d;
            if (ay <= 0.4142135623730951f * ax) d = 1;          // 0 deg
            else if (ay >= 2.414213562373095f * ax) d = 68;     // 90 deg
            else d = ((gx > 0.f) == (gy > 0.f)) ? 69 : 67;      // 45 / 135
            sbin[my][c] = (unsigned char)d;
        }
    }
    __syncthreads();

    // ---- NMS + double threshold + ballot; plane[img][word][row] ----
#pragma unroll
    for (int k = 0; k < 4; k++) {
        int ry = ty + 8 * k;   // 0..31
        const float* cp = &sm[ry + 1][tx + 1];
        float mag = cp[0];
        int d = sbin[ry + 1][tx + 1];
        float n1 = cp[d];
        float n2 = cp[-d];
        float nms = (mag >= n1 && mag >= n2) ? mag : 0.f;
        u64 strong = __ballot(nms >= 0.2f);
        u64 weak = __ballot(nms >= 0.1f);
        if (tx == 0) {
            size_t off = ((size_t)n * 8 + blockIdx.x) * H + (y0 + ry);
            strongP[off] = strong;
            weakP[off] = weak;
        }
    }
}

// ---------------------------------------------------------------------------
// Kernel 2: bit-parallel hysteresis (10 iters, exact via light cone) + diff
// count. One wave per 32x32 tile per image-pair; lane l holds row ty0-10+l
// (52 active lanes) as a 64-bit window covering x0-10 .. x0+53.
// Plane layout [img][word][row] -> lane-consecutive loads (coalesced).
// ---------------------------------------------------------------------------
__device__ __forceinline__ u64 ldw(const u64* p, int img, int y, int w, bool ok) {
    return (ok && w >= 0 && w < 8) ? p[((size_t)img * 8 + w) * H + y] : 0ULL;
}

__global__ __launch_bounds__(256) void k_hyst(const u64* __restrict__ strongP,
                                              const u64* __restrict__ weakP,
                                              unsigned int* __restrict__ partials) {
    __shared__ unsigned int part[4];
    const int wy = threadIdx.x >> 6;
    const int wave = blockIdx.x * 4 + wy;
    const int lane = threadIdx.x & 63;
    const int tile = wave & 255;
    const int pair = wave >> 8;          // 0..15
    const int tx0 = (tile & 15) * 32;
    const int ty0 = (tile >> 4) * 32;

    const int y = ty0 - 10 + lane;
    const bool rowok = (lane < 52) && (y >= 0) && (y < H);
    const int yc = rowok ? y : 0;        // clamped address, result masked below
    const int s = tx0 - 10;
    const int w0i = s >> 6;              // arithmetic shift: -10>>6 = -1
    const int r = s & 63;                // in {22,54}, never 0

    const int imgA = pair, imgB = pair + 16;
    u64 sA, wA, sB, wB;
    {
        u64 lo, hi;
        lo = ldw(strongP, imgA, yc, w0i, rowok); hi = ldw(strongP, imgA, yc, w0i + 1, rowok);
        sA = (lo >> r) | (hi << (64 - r));
        lo = ldw(weakP, imgA, yc, w0i, rowok);   hi = ldw(weakP, imgA, yc, w0i + 1, rowok);
        wA = (lo >> r) | (hi << (64 - r));
        lo = ldw(strongP, imgB, yc, w0i, rowok); hi = ldw(strongP, imgB, yc, w0i + 1, rowok);
        sB = (lo >> r) | (hi << (64 - r));
        lo = ldw(weakP, imgB, yc, w0i, rowok);   hi = ldw(weakP, imgB, yc, w0i + 1, rowok);
        wB = (lo >> r) | (hi << (64 - r));
    }

#pragma unroll
    for (int it = 0; it < 10; it++) {
        u64 up = __shfl_up(sA, 1), dn = __shfl_down(sA, 1);
        u64 t = up | sA | dn;
        sA |= (t | (t << 1) | (t >> 1)) & wA;
        up = __shfl_up(sB, 1); dn = __shfl_down(sB, 1);
        t = up | sB | dn;
        sB |= (t | (t << 1) | (t >> 1)) & wB;
    }

    // central 32x32: lanes 10..41, bits 10..41
    unsigned int c = 0;
    if (lane >= 10 && lane < 42) {
        const u64 mask = ((1ULL << 42) - (1ULL << 10));
        c = (unsigned int)__popcll((sA ^ sB) & mask);
    }
#pragma unroll
    for (int off = 32; off > 0; off >>= 1) c += __shfl_down(c, off);
    if (lane == 0) part[wy] = c;
    __syncthreads();
    if (threadIdx.x == 0)
        partials[blockIdx.x] = part[0] + part[1] + part[2] + part[3];
}

// ---------------------------------------------------------------------------
// Kernel 3: sum 1024 partials, scale, write scalar. One block.
// ---------------------------------------------------------------------------
__global__ __launch_bounds__(256) void k_final(const unsigned int* __restrict__ partials,
                                               float* __restrict__ out) {
    __shared__ unsigned int part[4];
    unsigned int c = 0;
    for (int i = threadIdx.x; i < 1024; i += 256) c += partials[i];
#pragma unroll
    for (int off = 32; off > 0; off >>= 1) c += __shfl_down(c, off);
    const int lane = threadIdx.x & 63;
    const int wy = threadIdx.x >> 6;
    if (lane == 0) part[wy] = c;
    __syncthreads();
    if (threadIdx.x == 0)
        out[0] = (float)(part[0] + part[1] + part[2] + part[3]) * (1.0f / 4194304.0f);
}

extern "C" void kernel_launch(void* const* d_in, const int* in_sizes, int n_in,
                              void* d_out, int out_size, void* d_ws, size_t ws_size,
                              hipStream_t stream) {
    const float* yhat = (const float*)d_in[0];
    const float* yy = (const float*)d_in[1];

    u64* strongP = (u64*)d_ws;                   // 32*8*512 u64 = 1 MB
    u64* weakP = strongP + (size_t)NIMG * H * 8; // 1 MB
    unsigned int* partials = (unsigned int*)(weakP + (size_t)NIMG * H * 8); // 4 KB

    dim3 eblk(64, 8);
    dim3 egrd(W / 64, H / TY, NIMG);
    k_edges<<<egrd, eblk, 0, stream>>>(yhat, yy, strongP, weakP);

    // 256 tiles x 16 pairs = 4096 waves, 4 waves/block
    k_hyst<<<1024, 256, 0, stream>>>(strongP, weakP, partials);
    k_final<<<1, 256, 0, stream>>>(partials, (float*)d_out);
}